// Round 2
// baseline (2352.005 us; speedup 1.0000x reference)
//
#include <hip/hip_runtime.h>
#include <cmath>

#define NN 50000
#define EE 800000
#define EB (EE + NN)   // 850000 edges incl self loops
#define INC 128
#define H1C 128        // heads*hid layer1
#define OUTC 64
#define EDIM 32

__device__ __forceinline__ void atomicMaxF(float* addr, float val) {
    int* ia = (int*)addr;
    int old = *ia;
    while (__int_as_float(old) < val) {
        int assumed = old;
        old = atomicCAS(ia, assumed, __float_as_int(val));
        if (old == assumed) break;
    }
}

__global__ void k_fill(float* p, int n, float v) {
    int i = blockIdx.x * blockDim.x + threadIdx.x;
    if (i < n) p[i] = v;
}

// accumulate per-node sum of incoming edge_attr + degree (for self-loop mean fill)
__global__ void k_loop_accum(const int* __restrict__ ei, const float* __restrict__ ea,
                             float* deg, float* la) {
    int idx = blockIdx.x * blockDim.x + threadIdx.x;
    if (idx >= EE * EDIM) return;
    int e = idx >> 5, d = idx & 31;
    int dst = ei[EE + e];
    atomicAdd(&la[dst * EDIM + d], ea[idx]);
    if (d == 0) atomicAdd(&deg[dst], 1.0f);
}

__global__ void k_loop_div(float* la, const float* __restrict__ deg) {
    int idx = blockIdx.x * blockDim.x + threadIdx.x;
    if (idx >= NN * EDIM) return;
    la[idx] = la[idx] / fmaxf(deg[idx >> 5], 1.0f);
}

// out[n][m] = sum_k x[n][k]*W[k][m] + b[m]; one block (M threads) per node
template <int K, int M>
__global__ void k_linear(const float* __restrict__ x, const float* __restrict__ W,
                         const float* __restrict__ b, float* __restrict__ out) {
    __shared__ float xs[K];
    int n = blockIdx.x;
    for (int i = threadIdx.x; i < K; i += M) xs[i] = x[(size_t)n * K + i];
    __syncthreads();
    int m = threadIdx.x;
    float acc = b[m];
#pragma unroll 8
    for (int k = 0; k < K; ++k) acc = fmaf(xs[k], W[k * M + m], acc);
    out[(size_t)n * M + m] = acc;
}

// ---------------- layer 1 (heads=2, C=64 -> 128 channels) ----------------

__global__ void k_logits1(const int* __restrict__ ei, const float* __restrict__ ea,
                          const float* __restrict__ la, const float* __restrict__ We,
                          const float* __restrict__ att,
                          const float* __restrict__ xl, const float* __restrict__ xr,
                          float* __restrict__ lg, float* lmax) {
    __shared__ float sWe[EDIM * H1C];   // 16 KB
    for (int i = threadIdx.x; i < EDIM * H1C; i += 256) sWe[i] = We[i];
    __syncthreads();
    int lane = threadIdx.x & 63;
    int e = blockIdx.x * 4 + (threadIdx.x >> 6);
    if (e >= EB) return;
    int src, dst; const float* er;
    if (e < EE) { src = ei[e]; dst = ei[EE + e]; er = ea + (size_t)e * EDIM; }
    else        { src = dst = e - EE;            er = la + (size_t)src * EDIM; }
    float m0 = xl[(size_t)src * H1C + lane]      + xr[(size_t)dst * H1C + lane];
    float m1 = xl[(size_t)src * H1C + 64 + lane] + xr[(size_t)dst * H1C + 64 + lane];
#pragma unroll
    for (int d = 0; d < EDIM; ++d) {
        float a = er[d];
        m0 = fmaf(a, sWe[d * H1C + lane], m0);
        m1 = fmaf(a, sWe[d * H1C + 64 + lane], m1);
    }
    m0 = m0 > 0.f ? m0 : 0.2f * m0;
    m1 = m1 > 0.f ? m1 : 0.2f * m1;
    float p0 = m0 * att[lane];
    float p1 = m1 * att[64 + lane];
    for (int off = 32; off; off >>= 1) { p0 += __shfl_xor(p0, off); p1 += __shfl_xor(p1, off); }
    if (lane == 0) {
        lg[(size_t)e * 2] = p0;
        lg[(size_t)e * 2 + 1] = p1;
        atomicMaxF(&lmax[dst * 2], p0);
        atomicMaxF(&lmax[dst * 2 + 1], p1);
    }
}

__global__ void k_expden1(const int* __restrict__ ei, float* lg,
                          const float* __restrict__ lmax, float* denom) {
    int idx = blockIdx.x * blockDim.x + threadIdx.x;
    if (idx >= EB * 2) return;
    int e = idx >> 1, hh = idx & 1;
    int dst = e < EE ? ei[EE + e] : e - EE;
    float ex = expf(lg[idx] - lmax[dst * 2 + hh]);
    lg[idx] = ex;
    atomicAdd(&denom[dst * 2 + hh], ex);
}

__global__ void k_agg1(const int* __restrict__ ei, const float* __restrict__ lg,
                       const float* __restrict__ denom, const float* __restrict__ xl,
                       float* hb) {
    int lane = threadIdx.x & 63;
    int e = blockIdx.x * 4 + (threadIdx.x >> 6);
    if (e >= EB) return;
    int src, dst;
    if (e < EE) { src = ei[e]; dst = ei[EE + e]; }
    else        { src = dst = e - EE; }
    float a0 = lg[(size_t)e * 2]     / (denom[dst * 2]     + 1e-16f);
    float a1 = lg[(size_t)e * 2 + 1] / (denom[dst * 2 + 1] + 1e-16f);
    atomicAdd(&hb[(size_t)dst * H1C + lane],      a0 * xl[(size_t)src * H1C + lane]);
    atomicAdd(&hb[(size_t)dst * H1C + 64 + lane], a1 * xl[(size_t)src * H1C + 64 + lane]);
}

__global__ void k_bias_elu(float* hb, const float* __restrict__ b) {
    int idx = blockIdx.x * blockDim.x + threadIdx.x;
    if (idx >= NN * H1C) return;
    float v = hb[idx] + b[idx & (H1C - 1)];
    hb[idx] = v > 0.f ? v : expm1f(v);
}

// ---------------- layer 2 (heads=1, C=64) ----------------

__global__ void k_logits2(const int* __restrict__ ei, const float* __restrict__ ea,
                          const float* __restrict__ la, const float* __restrict__ We,
                          const float* __restrict__ att,
                          const float* __restrict__ xl, const float* __restrict__ xr,
                          float* __restrict__ lg, float* lmax) {
    __shared__ float sWe[EDIM * OUTC];  // 8 KB
    for (int i = threadIdx.x; i < EDIM * OUTC; i += 256) sWe[i] = We[i];
    __syncthreads();
    int lane = threadIdx.x & 63;
    int e = blockIdx.x * 4 + (threadIdx.x >> 6);
    if (e >= EB) return;
    int src, dst; const float* er;
    if (e < EE) { src = ei[e]; dst = ei[EE + e]; er = ea + (size_t)e * EDIM; }
    else        { src = dst = e - EE;            er = la + (size_t)src * EDIM; }
    float m = xl[(size_t)src * OUTC + lane] + xr[(size_t)dst * OUTC + lane];
#pragma unroll
    for (int d = 0; d < EDIM; ++d) m = fmaf(er[d], sWe[d * OUTC + lane], m);
    m = m > 0.f ? m : 0.2f * m;
    float p = m * att[lane];
    for (int off = 32; off; off >>= 1) p += __shfl_xor(p, off);
    if (lane == 0) { lg[e] = p; atomicMaxF(&lmax[dst], p); }
}

__global__ void k_expden2(const int* __restrict__ ei, float* lg,
                          const float* __restrict__ lmax, float* denom) {
    int e = blockIdx.x * blockDim.x + threadIdx.x;
    if (e >= EB) return;
    int dst = e < EE ? ei[EE + e] : e - EE;
    float ex = expf(lg[e] - lmax[dst]);
    lg[e] = ex;
    atomicAdd(&denom[dst], ex);
}

__global__ void k_agg2(const int* __restrict__ ei, const float* __restrict__ lg,
                       const float* __restrict__ denom, const float* __restrict__ xl,
                       float* out) {
    int lane = threadIdx.x & 63;
    int e = blockIdx.x * 4 + (threadIdx.x >> 6);
    if (e >= EB) return;
    int src, dst;
    if (e < EE) { src = ei[e]; dst = ei[EE + e]; }
    else        { src = dst = e - EE; }
    float a = lg[e] / (denom[dst] + 1e-16f);
    atomicAdd(&out[(size_t)dst * OUTC + lane], a * xl[(size_t)src * OUTC + lane]);
}

__global__ void k_bias2(float* out, const float* __restrict__ b) {
    int idx = blockIdx.x * blockDim.x + threadIdx.x;
    if (idx >= NN * OUTC) return;
    out[idx] += b[idx & (OUTC - 1)];
}

extern "C" void kernel_launch(void* const* d_in, const int* in_sizes, int n_in,
                              void* d_out, int out_size, void* d_ws, size_t ws_size,
                              hipStream_t stream) {
    const float* x    = (const float*)d_in[0];
    const int*   ei   = (const int*)d_in[1];
    const float* ea   = (const float*)d_in[2];
    const float* Wl1  = (const float*)d_in[3];
    const float* bl1  = (const float*)d_in[4];
    const float* Wr1  = (const float*)d_in[5];
    const float* br1  = (const float*)d_in[6];
    const float* We1  = (const float*)d_in[7];
    const float* att1 = (const float*)d_in[8];
    const float* bias1= (const float*)d_in[9];
    const float* Wl2  = (const float*)d_in[10];
    const float* bl2  = (const float*)d_in[11];
    const float* Wr2  = (const float*)d_in[12];
    const float* br2  = (const float*)d_in[13];
    const float* We2  = (const float*)d_in[14];
    const float* att2 = (const float*)d_in[15];
    const float* bias2= (const float*)d_in[16];
    float* out = (float*)d_out;

    float* w     = (float*)d_ws;
    float* deg   = w;                       // NN
    float* la    = deg + NN;                // NN*32
    float* den1  = la + (size_t)NN * 32;    // NN*2
    float* den2  = den1 + NN * 2;           // NN
    float* hb    = den2 + NN;               // NN*128  (zero-region end)
    float* xl1   = hb + (size_t)NN * 128;   // NN*128
    float* xr1   = xl1 + (size_t)NN * 128;  // NN*128
    float* xl2   = xr1 + (size_t)NN * 128;  // NN*64
    float* xr2   = xl2 + (size_t)NN * 64;   // NN*64
    float* lmax1 = xr2 + (size_t)NN * 64;   // NN*2
    float* lmax2 = lmax1 + NN * 2;          // NN
    float* lg1   = lmax2 + NN;              // EB*2
    float* lg2   = lg1 + (size_t)EB * 2;    // EB

    size_t zero_floats = (size_t)NN * (1 + 32 + 2 + 1 + 128);
    hipMemsetAsync(w, 0, zero_floats * sizeof(float), stream);
    hipMemsetAsync(out, 0, (size_t)NN * OUTC * sizeof(float), stream);
    k_fill<<<(NN * 3 + 255) / 256, 256, 0, stream>>>(lmax1, NN * 3, -INFINITY);

    k_loop_accum<<<(EE * EDIM + 255) / 256, 256, 0, stream>>>(ei, ea, deg, la);
    k_loop_div<<<(NN * EDIM + 255) / 256, 256, 0, stream>>>(la, deg);

    k_linear<128, 128><<<NN, 128, 0, stream>>>(x, Wl1, bl1, xl1);
    k_linear<128, 128><<<NN, 128, 0, stream>>>(x, Wr1, br1, xr1);

    int eb4 = (EB + 3) / 4;
    k_logits1<<<eb4, 256, 0, stream>>>(ei, ea, la, We1, att1, xl1, xr1, lg1, lmax1);
    k_expden1<<<(EB * 2 + 255) / 256, 256, 0, stream>>>(ei, lg1, lmax1, den1);
    k_agg1<<<eb4, 256, 0, stream>>>(ei, lg1, den1, xl1, hb);
    k_bias_elu<<<(NN * H1C + 255) / 256, 256, 0, stream>>>(hb, bias1);

    k_linear<128, 64><<<NN, 64, 0, stream>>>(hb, Wl2, bl2, xl2);
    k_linear<128, 64><<<NN, 64, 0, stream>>>(hb, Wr2, br2, xr2);

    k_logits2<<<eb4, 256, 0, stream>>>(ei, ea, la, We2, att2, xl2, xr2, lg2, lmax2);
    k_expden2<<<(EB + 255) / 256, 256, 0, stream>>>(ei, lg2, lmax2, den2);
    k_agg2<<<eb4, 256, 0, stream>>>(ei, lg2, den2, xl2, out);
    k_bias2<<<(NN * OUTC + 255) / 256, 256, 0, stream>>>(out, bias2);
}

// Round 6
// 1194.030 us; speedup vs baseline: 1.9698x; 1.9698x over previous
//
#include <hip/hip_runtime.h>
#include <cmath>

#define NN 50000
#define EE 800000
#define H1C 128        // heads*hid layer1
#define OUTC 64
#define EDIM 32
#define NBLK 196       // ceil(NN/256)

// ---------------- CSR build ----------------

__global__ void k_hist(const int* __restrict__ ei, int* deg) {
    int e = blockIdx.x * 256 + threadIdx.x;
    if (e < EE) atomicAdd(&deg[ei[EE + e]], 1);
}

__global__ void k_scan_block(const int* __restrict__ deg, int* offs, int* bsum) {
    __shared__ int s[256];
    int t = threadIdx.x;
    int gid = blockIdx.x * 256 + t;
    int v = (gid < NN) ? deg[gid] : 0;
    s[t] = v;
    __syncthreads();
    for (int off = 1; off < 256; off <<= 1) {
        int add = (t >= off) ? s[t - off] : 0;
        __syncthreads();
        s[t] += add;
        __syncthreads();
    }
    if (gid < NN) offs[gid] = s[t] - v;          // exclusive within block
    if (t == 255) bsum[blockIdx.x] = s[255];
}

__global__ void k_scan_top(const int* __restrict__ bsum, int* bexcl) {
    __shared__ int s[256];
    int t = threadIdx.x;
    int v = (t < NBLK) ? bsum[t] : 0;
    s[t] = v;
    __syncthreads();
    for (int off = 1; off < 256; off <<= 1) {
        int add = (t >= off) ? s[t - off] : 0;
        __syncthreads();
        s[t] += add;
        __syncthreads();
    }
    bexcl[t] = s[t] - v;
}

__global__ void k_scan_add(int* offs, const int* __restrict__ bexcl) {
    int gid = blockIdx.x * 256 + threadIdx.x;
    if (gid < NN) offs[gid] += bexcl[blockIdx.x];
    if (gid == 0) offs[NN] = EE;
}

__global__ void k_scatter(const int* __restrict__ ei, const int* __restrict__ offs,
                          int* deg, int2* esort) {
    int e = blockIdx.x * 256 + threadIdx.x;
    if (e >= EE) return;
    int dst = ei[EE + e];
    int idx = atomicSub(&deg[dst], 1) - 1;
    esort[offs[dst] + idx] = make_int2(ei[e], e);
}

// ---------------- fused pair of linears: oa = x@Wa+ba, ob = x@Wb+bb ----------------
// 32 nodes per block; thread t owns output column m of matrix (t<MO ? a : b)

template <int MO>
__global__ void k_lin_pair(const float* __restrict__ x,
                           const float* __restrict__ Wa, const float* __restrict__ ba,
                           const float* __restrict__ Wb, const float* __restrict__ bb,
                           float* __restrict__ oa, float* __restrict__ ob) {
    __shared__ float xsT[128][36];   // transposed tile, padded (36*4B = 16B-aligned rows)
    int n0 = blockIdx.x * 32;
    int nthr = 2 * MO;
    for (int idx = threadIdx.x; idx < 32 * 128; idx += nthr) {
        int n = idx >> 7, k = idx & 127;
        xsT[k][n] = (n0 + n < NN) ? x[(size_t)(n0 + n) * 128 + k] : 0.f;
    }
    __syncthreads();
    int t = threadIdx.x;
    const float* W  = (t < MO) ? Wa : Wb;
    const float* bp = (t < MO) ? ba : bb;
    float* op       = (t < MO) ? oa : ob;
    int m = (t < MO) ? t : t - MO;
    float bv = bp[m];
    float acc[32];
#pragma unroll
    for (int n = 0; n < 32; ++n) acc[n] = bv;
#pragma unroll 2
    for (int k = 0; k < 128; ++k) {
        float w = W[k * MO + m];
        const float4* row = reinterpret_cast<const float4*>(&xsT[k][0]);
#pragma unroll
        for (int c = 0; c < 8; ++c) {
            float4 v = row[c];
            acc[4 * c + 0] = fmaf(v.x, w, acc[4 * c + 0]);
            acc[4 * c + 1] = fmaf(v.y, w, acc[4 * c + 1]);
            acc[4 * c + 2] = fmaf(v.z, w, acc[4 * c + 2]);
            acc[4 * c + 3] = fmaf(v.w, w, acc[4 * c + 3]);
        }
    }
#pragma unroll
    for (int n = 0; n < 32; ++n)
        if (n0 + n < NN) op[(size_t)(n0 + n) * MO + m] = acc[n];
}

// ---------------- fused edge phase, layer 1 (2 heads x 64) ----------------

__device__ __forceinline__ void edge_upd1(float xl0, float xl1, float av,
                                          float xr0, float xr1, float a0, float a1,
                                          const float* sWe, int lane,
                                          float& mr0, float& mr1, float& s0, float& s1,
                                          float& acc0, float& acc1) {
    float m0 = xl0 + xr0, m1 = xl1 + xr1;
#pragma unroll
    for (int d = 0; d < EDIM; ++d) {
        float a = __shfl(av, d);
        m0 = fmaf(a, sWe[d * H1C + lane], m0);
        m1 = fmaf(a, sWe[d * H1C + 64 + lane], m1);
    }
    m0 = m0 > 0.f ? m0 : 0.2f * m0;
    m1 = m1 > 0.f ? m1 : 0.2f * m1;
    float p0 = m0 * a0, p1 = m1 * a1;
#pragma unroll
    for (int off = 32; off; off >>= 1) { p0 += __shfl_xor(p0, off); p1 += __shfl_xor(p1, off); }
    float nm = fmaxf(mr0, p0);
    float sc = __expf(mr0 - nm), e = __expf(p0 - nm);
    s0 = s0 * sc + e; acc0 = fmaf(acc0, sc, e * xl0); mr0 = nm;
    nm = fmaxf(mr1, p1);
    sc = __expf(mr1 - nm); e = __expf(p1 - nm);
    s1 = s1 * sc + e; acc1 = fmaf(acc1, sc, e * xl1); mr1 = nm;
}

__global__ void __launch_bounds__(256) k_l1(
    const int2* __restrict__ esort, const int* __restrict__ offs,
    const float* __restrict__ ea, const float* __restrict__ We,
    const float* __restrict__ att, const float* __restrict__ xl,
    const float* __restrict__ xr, const float* __restrict__ bias,
    float* __restrict__ hb) {
    __shared__ float sWe[EDIM * H1C];   // 16 KB
    for (int i = threadIdx.x; i < EDIM * H1C; i += 256) sWe[i] = We[i];
    __syncthreads();
    int lane = threadIdx.x & 63;
    int dst = (blockIdx.x << 2) + (threadIdx.x >> 6);
    if (dst >= NN) return;
    int beg = offs[dst], end = offs[dst + 1];
    float a0 = att[lane], a1 = att[64 + lane];
    size_t db = (size_t)dst * H1C;
    float xr0 = xr[db + lane], xr1 = xr[db + 64 + lane];
    float mr0 = -INFINITY, mr1 = -INFINITY;
    float s0 = 0.f, s1 = 0.f, acc0 = 0.f, acc1 = 0.f, easum = 0.f;

    float xl0 = 0.f, xl1 = 0.f, av = 0.f;
    if (beg < end) {                    // preload first edge
        int2 ed = esort[beg];
        size_t sb = (size_t)ed.x * H1C;
        xl0 = xl[sb + lane]; xl1 = xl[sb + 64 + lane];
        av = ea[(size_t)ed.y * EDIM + (lane & 31)];
    }
    for (int j = beg; j < end; ++j) {
        float cxl0 = xl0, cxl1 = xl1, cav = av;
        if (j + 1 < end) {              // issue next edge's loads before compute
            int2 ed = esort[j + 1];
            size_t sb = (size_t)ed.x * H1C;
            xl0 = xl[sb + lane]; xl1 = xl[sb + 64 + lane];
            av = ea[(size_t)ed.y * EDIM + (lane & 31)];
        }
        easum += cav;
        edge_upd1(cxl0, cxl1, cav, xr0, xr1, a0, a1, sWe, lane, mr0, mr1, s0, s1, acc0, acc1);
    }
    // self loop: attr = mean of incoming edge attrs (0 if no edges)
    int deg = end - beg;
    float lav = easum * ((deg > 0) ? (1.f / (float)deg) : 1.f);
    float sxl0 = xl[db + lane], sxl1 = xl[db + 64 + lane];
    edge_upd1(sxl0, sxl1, lav, xr0, xr1, a0, a1, sWe, lane, mr0, mr1, s0, s1, acc0, acc1);

    float h0 = acc0 / (s0 + 1e-16f) + bias[lane];
    float h1 = acc1 / (s1 + 1e-16f) + bias[64 + lane];
    hb[db + lane]      = h0 > 0.f ? h0 : expm1f(h0);
    hb[db + 64 + lane] = h1 > 0.f ? h1 : expm1f(h1);
}

// ---------------- fused edge phase, layer 2 (1 head x 64) ----------------

__device__ __forceinline__ void edge_upd2(float xlv, float av, float xrv, float a,
                                          const float* sWe, int lane,
                                          float& mr, float& s, float& acc) {
    float m = xlv + xrv;
#pragma unroll
    for (int d = 0; d < EDIM; ++d)
        m = fmaf(__shfl(av, d), sWe[d * OUTC + lane], m);
    m = m > 0.f ? m : 0.2f * m;
    float p = m * a;
#pragma unroll
    for (int off = 32; off; off >>= 1) p += __shfl_xor(p, off);
    float nm = fmaxf(mr, p);
    float sc = __expf(mr - nm), e = __expf(p - nm);
    s = s * sc + e; acc = fmaf(acc, sc, e * xlv); mr = nm;
}

__global__ void __launch_bounds__(256) k_l2(
    const int2* __restrict__ esort, const int* __restrict__ offs,
    const float* __restrict__ ea, const float* __restrict__ We,
    const float* __restrict__ att, const float* __restrict__ xl,
    const float* __restrict__ xr, const float* __restrict__ bias,
    float* __restrict__ out) {
    __shared__ float sWe[EDIM * OUTC];  // 8 KB
    for (int i = threadIdx.x; i < EDIM * OUTC; i += 256) sWe[i] = We[i];
    __syncthreads();
    int lane = threadIdx.x & 63;
    int dst = (blockIdx.x << 2) + (threadIdx.x >> 6);
    if (dst >= NN) return;
    int beg = offs[dst], end = offs[dst + 1];
    float a = att[lane];
    size_t db = (size_t)dst * OUTC;
    float xrv = xr[db + lane];
    float mr = -INFINITY, s = 0.f, acc = 0.f, easum = 0.f;

    float xlv = 0.f, av = 0.f;
    if (beg < end) {
        int2 ed = esort[beg];
        xlv = xl[(size_t)ed.x * OUTC + lane];
        av = ea[(size_t)ed.y * EDIM + (lane & 31)];
    }
    for (int j = beg; j < end; ++j) {
        float cxl = xlv, cav = av;
        if (j + 1 < end) {
            int2 ed = esort[j + 1];
            xlv = xl[(size_t)ed.x * OUTC + lane];
            av = ea[(size_t)ed.y * EDIM + (lane & 31)];
        }
        easum += cav;
        edge_upd2(cxl, cav, xrv, a, sWe, lane, mr, s, acc);
    }
    int deg = end - beg;
    float lav = easum * ((deg > 0) ? (1.f / (float)deg) : 1.f);
    float sxl = xl[db + lane];
    edge_upd2(sxl, lav, xrv, a, sWe, lane, mr, s, acc);

    out[db + lane] = acc / (s + 1e-16f) + bias[lane];
}

// ---------------- launch ----------------

extern "C" void kernel_launch(void* const* d_in, const int* in_sizes, int n_in,
                              void* d_out, int out_size, void* d_ws, size_t ws_size,
                              hipStream_t stream) {
    const float* x    = (const float*)d_in[0];
    const int*   ei   = (const int*)d_in[1];
    const float* ea   = (const float*)d_in[2];
    const float* Wl1  = (const float*)d_in[3];
    const float* bl1  = (const float*)d_in[4];
    const float* Wr1  = (const float*)d_in[5];
    const float* br1  = (const float*)d_in[6];
    const float* We1  = (const float*)d_in[7];
    const float* att1 = (const float*)d_in[8];
    const float* bias1= (const float*)d_in[9];
    const float* Wl2  = (const float*)d_in[10];
    const float* bl2  = (const float*)d_in[11];
    const float* Wr2  = (const float*)d_in[12];
    const float* br2  = (const float*)d_in[13];
    const float* We2  = (const float*)d_in[14];
    const float* att2 = (const float*)d_in[15];
    const float* bias2= (const float*)d_in[16];
    float* out = (float*)d_out;

    char* w = (char*)d_ws;
    int2* esort = (int2*)w;                 w += (size_t)EE * 8;        // 6.4 MB
    int*  offs  = (int*)w;                  w += (size_t)(NN + 4) * 4;
    int*  bsum  = (int*)w;                  w += 256 * 4;
    int*  bexcl = (int*)w;                  w += 256 * 4;
    int*  deg   = (int*)w;                  w += (size_t)NN * 4;
    float* xl1  = (float*)w;                w += (size_t)NN * H1C * 4;
    float* xr1  = (float*)w;                w += (size_t)NN * H1C * 4;
    float* hb   = (float*)w;                w += (size_t)NN * H1C * 4;
    float* xl2  = (float*)w;                w += (size_t)NN * OUTC * 4;
    float* xr2  = (float*)w;                w += (size_t)NN * OUTC * 4;

    hipMemsetAsync(deg, 0, (size_t)NN * 4, stream);

    // CSR build (edges sorted by dst)
    k_hist<<<(EE + 255) / 256, 256, 0, stream>>>(ei, deg);
    k_scan_block<<<NBLK, 256, 0, stream>>>(deg, offs, bsum);
    k_scan_top<<<1, 256, 0, stream>>>(bsum, bexcl);
    k_scan_add<<<NBLK, 256, 0, stream>>>(offs, bexcl);
    k_scatter<<<(EE + 255) / 256, 256, 0, stream>>>(ei, offs, deg, esort);

    // layer 1
    k_lin_pair<128><<<(NN + 31) / 32, 256, 0, stream>>>(x, Wl1, bl1, Wr1, br1, xl1, xr1);
    k_l1<<<(NN + 3) / 4, 256, 0, stream>>>(esort, offs, ea, We1, att1, xl1, xr1, bias1, hb);

    // layer 2
    k_lin_pair<64><<<(NN + 31) / 32, 128, 0, stream>>>(hb, Wl2, bl2, Wr2, br2, xl2, xr2);
    k_l2<<<(NN + 3) / 4, 256, 0, stream>>>(esort, offs, ea, We2, att2, xl2, xr2, bias2, out);
}